// Round 6
// baseline (587.371 us; speedup 1.0000x reference)
//
#include <hip/hip_runtime.h>
#include <hip/hip_bf16.h>

#define S_ 1024
#define P_ 1024
#define B_ 4
#define E_ 1024
#define J_ 2048
#define H_ 16
#define I_ 64

typedef __bf16 bf16_t;
typedef __bf16 bf16x8 __attribute__((ext_vector_type(8)));
typedef __bf16 bf16x4 __attribute__((ext_vector_type(4)));
typedef float f32x4 __attribute__((ext_vector_type(4)));

#define MFMA16(a, b, c) __builtin_amdgcn_mfma_f32_16x16x32_bf16(a, b, c, 0, 0, 0)

// XOR-granule swizzle for stride-64 bf16 LDS tiles.
#define SWZ(r, c) (((r) << 6) + ((((((c) >> 3)) ^ ((r) & 7)) << 3)) + ((c) & 7))

typedef const __attribute__((address_space(1))) void* gp1_t;
typedef __attribute__((address_space(3))) void* lp3_t;
#define GLOAD16(g, l) __builtin_amdgcn_global_load_lds((gp1_t)(g), (lp3_t)(l), 16, 0, 0)

// ---------------- fp32 -> bf16 convert ----------------
__global__ __launch_bounds__(256) void cvt_kernel(const float* __restrict__ src,
                                                  bf16_t* __restrict__ dst, int n) {
    int i = (blockIdx.x * 256 + threadIdx.x) * 4;
    if (i < n) {
        float4 v = *(const float4*)(src + i);
        bf16x4 o = {(bf16_t)v.x, (bf16_t)v.y, (bf16_t)v.z, (bf16_t)v.w};
        *(bf16x4*)(dst + i) = o;
    }
}

// ---------------- W (K x N) fp32 -> W^T (N x K) bf16 ----------------
__global__ void transpose_cvt(const float* __restrict__ W, bf16_t* __restrict__ Wt,
                              int K, int N) {
    __shared__ float tile[32][33];
    int n0 = blockIdx.x * 32, k0 = blockIdx.y * 32;
    int x = threadIdx.x, y = threadIdx.y;
    for (int i = 0; i < 32; i += 8)
        tile[y + i][x] = W[(size_t)(k0 + y + i) * N + n0 + x];
    __syncthreads();
    for (int i = 0; i < 32; i += 8)
        Wt[(size_t)(n0 + y + i) * K + k0 + x] = (bf16_t)tile[x][y + i];
}

// ---------------- bf16 MFMA GEMM (global_load_lds staging, swizzled) ----------------
template <int EPI>
__global__ __launch_bounds__(256) void gemm_bf16(
    const bf16_t* __restrict__ A, const bf16_t* __restrict__ Bt,
    int M, int N, int K,
    bf16_t* __restrict__ out0, bf16_t* __restrict__ out1,
    const float* __restrict__ add0, const float* __restrict__ add1,
    float* __restrict__ outf) {
    __shared__ __attribute__((aligned(16))) bf16_t Al[128 * 64];
    __shared__ __attribute__((aligned(16))) bf16_t Bl[128 * 64];
    int tid = threadIdx.x;
    int wave = tid >> 6, lane = tid & 63, quad = lane >> 4, l16 = lane & 15;
    int m0 = blockIdx.y * 128, n0 = blockIdx.x * 128;
    int wm = (wave & 1) * 64, wn = (wave >> 1) * 64;

    int lrow = lane >> 3;
    int lgr = (lane & 7) ^ (lrow & 7);
    const bf16_t* gsrc = (wave < 2)
        ? A + (size_t)(m0 + (wave & 1) * 64 + lrow) * K + lgr * 8
        : Bt + (size_t)(n0 + (wave & 1) * 64 + lrow) * K + lgr * 8;
    bf16_t* lds_wave = ((wave < 2) ? Al : Bl) + (wave & 1) * 4096;

    f32x4 zero = {0.f, 0.f, 0.f, 0.f};
    f32x4 acc[4][4];
    #pragma unroll
    for (int i = 0; i < 4; i++)
        #pragma unroll
        for (int j = 0; j < 4; j++) acc[i][j] = zero;

    for (int k0 = 0; k0 < K; k0 += 64) {
        __syncthreads();
        #pragma unroll
        for (int q = 0; q < 8; q++)
            GLOAD16(gsrc + (size_t)(q * 8) * K + k0, lds_wave + q * 512);
        __syncthreads();
        #pragma unroll
        for (int ks = 0; ks < 2; ks++) {
            bf16x8 af[4], bfr[4];
            #pragma unroll
            for (int i = 0; i < 4; i++)
                af[i] = *(const bf16x8*)&Al[SWZ(wm + i * 16 + l16, ks * 32 + quad * 8)];
            #pragma unroll
            for (int j = 0; j < 4; j++)
                bfr[j] = *(const bf16x8*)&Bl[SWZ(wn + j * 16 + l16, ks * 32 + quad * 8)];
            #pragma unroll
            for (int i = 0; i < 4; i++)
                #pragma unroll
                for (int j = 0; j < 4; j++) acc[i][j] = MFMA16(af[i], bfr[j], acc[i][j]);
        }
    }
    #pragma unroll
    for (int i = 0; i < 4; i++)
        #pragma unroll
        for (int j = 0; j < 4; j++)
            #pragma unroll
            for (int reg = 0; reg < 4; reg++) {
                int m = m0 + wm + i * 16 + quad * 4 + reg;
                int n = n0 + wn + j * 16 + l16;
                float v = acc[i][j][reg];
                if (EPI == 0) {
                    out0[(size_t)m * N + n] = (bf16_t)v;
                } else if (EPI == 1) {
                    out0[(size_t)m * N + n] = (bf16_t)(v + add0[n]);
                    out1[(size_t)m * N + n] = (bf16_t)(v + add1[n]);
                } else {
                    outf[(size_t)m * N + n] = v + add0[(size_t)m * N + n];
                }
            }
}

// ---------------- V transpose: kvb values -> Vt_g[b*1024+i][j] ----------------
__global__ __launch_bounds__(256) void vtrans_kernel(const bf16_t* __restrict__ kvb,
                                                     bf16_t* __restrict__ vtg) {
    __shared__ bf16_t t[64][72];
    int j0 = blockIdx.x * 64, c0 = blockIdx.y * 64, b = blockIdx.z;
    int r = threadIdx.x >> 3, sg = (threadIdx.x & 7) * 8;
    #pragma unroll
    for (int hrow = 0; hrow < 64; hrow += 32) {
        int row = r + hrow;
        *(uint4*)&t[row][sg] =
            *(const uint4*)&kvb[((size_t)(j0 + row) * B_ + b) * 2048 + 1024 + c0 + sg];
    }
    __syncthreads();
    #pragma unroll
    for (int hrow = 0; hrow < 64; hrow += 32) {
        int hi = r + hrow;
        bf16x8 v;
        #pragma unroll
        for (int e = 0; e < 8; e++) v[e] = t[sg + e][hi];
        *(bf16x8*)&vtg[((size_t)(b * 1024 + c0 + hi)) * 2048 + j0 + sg] = v;
    }
}

// ---------------- flash attention: wave-autonomous, ZERO barriers ----------------
// grid (16, B*H), 4 waves/block. Wave handles s-group g = wave*16 + blockIdx.x
// (16 q-rows, full j-range; per-block tile count ~constant for balance).
// K/P/V fragments loaded global->reg directly (coalesced 16-line dwordx4).
// Only LDS: per-wave 2KB Prob slab (wave-ordered DS, no sync needed).
__global__ __launch_bounds__(256, 3) void flash_kernel(
    const bf16_t* __restrict__ qu, const bf16_t* __restrict__ qv,
    const bf16_t* __restrict__ kv, const bf16_t* __restrict__ vtg,
    const bf16_t* __restrict__ pm, bf16_t* __restrict__ awv) {
    __shared__ __attribute__((aligned(16))) bf16_t Prob[4 * 16 * 64];  // 8 KB

    int tid = threadIdx.x;
    int wave = tid >> 6, lane = tid & 63, quad = lane >> 4, l16 = lane & 15;
    int b = blockIdx.y >> 4, h = blockIdx.y & 15;
    int g = wave * 16 + blockIdx.x;            // 0..63
    int srow0 = g * 16;
    int nt = (g + 68) >> 2;                    // ceil((1040+16g)/64)

    const bf16_t* qub = qu + ((size_t)(srow0 + l16) * B_ + b) * 1024 + h * 64 + quad * 8;
    const bf16_t* qvb = qv + ((size_t)(srow0 + l16) * B_ + b) * 1024 + h * 64 + quad * 8;
    bf16x8 aqu0 = *(const bf16x8*)(qub);
    bf16x8 aqu1 = *(const bf16x8*)(qub + 32);
    bf16x8 aqv0 = *(const bf16x8*)(qvb);
    bf16x8 aqv1 = *(const bf16x8*)(qvb + 32);

    f32x4 zero = {0.f, 0.f, 0.f, 0.f};
    f32x4 accO[4];
    #pragma unroll
    for (int ot = 0; ot < 4; ot++) accO[ot] = zero;
    float lrowp[4] = {0.f, 0.f, 0.f, 0.f};

    const int w0 = 1008 - srow0;               // P window base (+ j0)
    const float SCL = 0.125f * 1.44269504088896f;
    bf16_t* ProbW = Prob + (wave << 10);

    // base pointers for fragment loads (lane-invariant parts hoisted)
    const bf16_t* kbase = kv + (size_t)b * 2048 + h * 64 + quad * 8;      // + (j)*B*2048 + ks*32
    const bf16_t* vbase = vtg + ((size_t)(b * 1024 + h * 64 + l16)) * 2048 + quad * 8;
    const bf16_t* pbase = pm + h * 64 + quad * 8;

    for (int it = 0; it < nt; it++) {
        int j0 = it * 64;

        // ---- K fragments (8 x dwordx4, coalesced 16-line) ----
        bf16x8 bk[2][4];
        #pragma unroll
        for (int t = 0; t < 4; t++) {
            const bf16_t* kp = kbase + (size_t)(j0 + t * 16 + l16) * (B_ * 2048);
            bk[0][t] = *(const bf16x8*)(kp);
            bk[1][t] = *(const bf16x8*)(kp + 32);
        }
        // ---- P fragments (10 x dwordx4) ----
        bf16x8 bp[2][5];
        #pragma unroll
        for (int t = 0; t < 5; t++) {
            int prr = w0 + j0 + t * 16 + l16;
            if (prr > J_ - 1) prr = J_ - 1;     // clamped rows only feed masked cols
            const bf16_t* pp = pbase + (size_t)prr * 1024;
            bp[0][t] = *(const bf16x8*)(pp);
            bp[1][t] = *(const bf16x8*)(pp + 32);
        }

        // ---- scores ----
        f32x4 cs[4], ep[5];
        #pragma unroll
        for (int t = 0; t < 4; t++) cs[t] = zero;
        #pragma unroll
        for (int t = 0; t < 5; t++) ep[t] = zero;
        #pragma unroll
        for (int ks = 0; ks < 2; ks++) {
            bf16x8 aq = ks ? aqu1 : aqu0;
            #pragma unroll
            for (int t = 0; t < 4; t++) cs[t] = MFMA16(aq, bk[ks][t], cs[t]);
        }
        #pragma unroll
        for (int ks = 0; ks < 2; ks++) {
            bf16x8 aq = ks ? aqv1 : aqv0;
            #pragma unroll
            for (int t = 0; t < 5; t++) ep[t] = MFMA16(aq, bp[ks][t], ep[t]);
        }

        // ---- V fragments (issued早 so they overlap softmax) ----
        bf16x8 bv[2][4];
        #pragma unroll
        for (int ot = 0; ot < 4; ot++) {
            const bf16_t* vp = vbase + (size_t)(ot * 16) * 2048 + j0;
            bv[0][ot] = *(const bf16x8*)(vp);
            bv[1][ot] = *(const bf16x8*)(vp + 32);
        }

        // ---- rel-shift gather + fixed-max softmax ----
        #pragma unroll
        for (int reg = 0; reg < 4; reg++) {
            int r = quad * 4 + reg;
            int s = srow0 + r;
            int idx = l16 + 15 - r;
            int srcl = quad * 16 + (idx & 15);
            float sh[5];
            #pragma unroll
            for (int t = 0; t < 5; t++) sh[t] = __shfl(ep[t][reg], srcl);
            float psum = 0.f;
            #pragma unroll
            for (int t = 0; t < 4; t++) {
                float pos = (idx < 16) ? sh[t] : sh[t + 1];
                float p = exp2f((cs[t][reg] + pos) * SCL);
                p = (j0 + t * 16 + l16 > P_ + s) ? 0.f : p;
                ProbW[SWZ(r, t * 16 + l16)] = (bf16_t)p;
                psum += p;
            }
            lrowp[reg] += psum;
        }

        // ---- PV (Prob round-trip is wave-private; DS ops wave-ordered) ----
        #pragma unroll
        for (int ks = 0; ks < 2; ks++) {
            bf16x8 pa = *(const bf16x8*)&ProbW[SWZ(l16, ks * 32 + quad * 8)];
            #pragma unroll
            for (int ot = 0; ot < 4; ot++) accO[ot] = MFMA16(pa, bv[ks][ot], accO[ot]);
        }
    }

    // ---- epilogue: row-sum reduce, normalize, store ----
    #pragma unroll
    for (int reg = 0; reg < 4; reg++) {
        float l = lrowp[reg];
        #pragma unroll
        for (int d = 1; d < 16; d <<= 1) l += __shfl_xor(l, d);
        float inv = 1.0f / l;
        int r = quad * 4 + reg;
        size_t rowoff = ((size_t)(srow0 + r) * B_ + b) * 1024 + h * 64;
        #pragma unroll
        for (int ot = 0; ot < 4; ot++)
            awv[rowoff + ot * 16 + l16] = (bf16_t)(accO[ot][reg] * inv);
    }
}

// ---------------- LayerNorm over E=1024 ----------------
__global__ __launch_bounds__(256) void ln_kernel(const float* __restrict__ x,
                                                 const float* __restrict__ gamma,
                                                 const float* __restrict__ beta,
                                                 float* __restrict__ out) {
    int row = blockIdx.x, tid = threadIdx.x;
    int lane = tid & 63, wave = tid >> 6;
    float4 v = ((const float4*)(x + (size_t)row * 1024))[tid];
    float s = v.x + v.y + v.z + v.w;
    float ss = v.x * v.x + v.y * v.y + v.z * v.z + v.w * v.w;
    #pragma unroll
    for (int sh = 1; sh < 64; sh <<= 1) { s += __shfl_xor(s, sh); ss += __shfl_xor(ss, sh); }
    __shared__ float red[8];
    if (lane == 0) { red[wave] = s; red[4 + wave] = ss; }
    __syncthreads();
    s = red[0] + red[1] + red[2] + red[3];
    ss = red[4] + red[5] + red[6] + red[7];
    float mean = s * (1.f / 1024.f);
    float var = ss * (1.f / 1024.f) - mean * mean;
    float inv = rsqrtf(var + 1e-5f);
    float4 g = ((const float4*)gamma)[tid];
    float4 bt = ((const float4*)beta)[tid];
    float4 o;
    o.x = (v.x - mean) * inv * g.x + bt.x;
    o.y = (v.y - mean) * inv * g.y + bt.y;
    o.z = (v.z - mean) * inv * g.z + bt.z;
    o.w = (v.w - mean) * inv * g.w + bt.w;
    ((float4*)(out + (size_t)row * 1024))[tid] = o;
}

extern "C" void kernel_launch(void* const* d_in, const int* in_sizes, int n_in,
                              void* d_out, int out_size, void* d_ws, size_t ws_size,
                              hipStream_t stream) {
    const float* inputMHA = (const float*)d_in[0];
    const float* posEmb   = (const float*)d_in[1];
    const float* memory   = (const float*)d_in[2];
    const float* u        = (const float*)d_in[3];
    const float* v        = (const float*)d_in[4];
    const float* W_kv     = (const float*)d_in[6];
    const float* W_q      = (const float*)d_in[7];
    const float* W_p      = (const float*)d_in[8];
    const float* W_o      = (const float*)d_in[9];
    const float* gamma    = (const float*)d_in[10];
    const float* beta     = (const float*)d_in[11];
    float* out = (float*)d_out;

    char* ws = (char*)d_ws;
    size_t off = 0;
    auto alloc = [&](size_t bytes) -> void* {
        void* p = ws + off;
        off += (bytes + 255) & ~(size_t)255;
        return p;
    };
    bf16_t* Xbf  = (bf16_t*)alloc((size_t)J_ * B_ * E_ * 2);
    bf16_t* Wkvt = (bf16_t*)alloc((size_t)2048 * 1024 * 2);
    bf16_t* Wqt  = (bf16_t*)alloc((size_t)1024 * 1024 * 2);
    bf16_t* Wpt  = (bf16_t*)alloc((size_t)1024 * 1024 * 2);
    bf16_t* Wot  = (bf16_t*)alloc((size_t)1024 * 1024 * 2);
    bf16_t* Pemb = (bf16_t*)alloc((size_t)2048 * 1024 * 2);
    bf16_t* kvb  = (bf16_t*)alloc((size_t)8192 * 2048 * 2);
    bf16_t* vtg  = (bf16_t*)alloc((size_t)B_ * 1024 * 2048 * 2);
    bf16_t* qub  = (bf16_t*)alloc((size_t)4096 * 1024 * 2);
    bf16_t* qvb  = (bf16_t*)alloc((size_t)4096 * 1024 * 2);
    bf16_t* pb   = (bf16_t*)alloc((size_t)2048 * 1024 * 2);
    bf16_t* awvb = (bf16_t*)alloc((size_t)4096 * 1024 * 2);
    float*  opre = (float*)alloc((size_t)4096 * 1024 * 4);

    cvt_kernel<<<P_ * B_ * E_ / 1024, 256, 0, stream>>>(memory, Xbf, P_ * B_ * E_);
    cvt_kernel<<<S_ * B_ * E_ / 1024, 256, 0, stream>>>(inputMHA, Xbf + (size_t)P_ * B_ * E_,
                                                        S_ * B_ * E_);
    cvt_kernel<<<J_ * E_ / 1024, 256, 0, stream>>>(posEmb, Pemb, J_ * E_);
    transpose_cvt<<<dim3(2048 / 32, 1024 / 32), dim3(32, 8), 0, stream>>>(W_kv, Wkvt, 1024, 2048);
    transpose_cvt<<<dim3(1024 / 32, 1024 / 32), dim3(32, 8), 0, stream>>>(W_q, Wqt, 1024, 1024);
    transpose_cvt<<<dim3(1024 / 32, 1024 / 32), dim3(32, 8), 0, stream>>>(W_p, Wpt, 1024, 1024);
    transpose_cvt<<<dim3(1024 / 32, 1024 / 32), dim3(32, 8), 0, stream>>>(W_o, Wot, 1024, 1024);

    gemm_bf16<0><<<dim3(2048 / 128, 8192 / 128), 256, 0, stream>>>(
        Xbf, Wkvt, 8192, 2048, 1024, kvb, nullptr, nullptr, nullptr, nullptr);
    gemm_bf16<1><<<dim3(1024 / 128, 4096 / 128), 256, 0, stream>>>(
        Xbf + (size_t)P_ * B_ * E_, Wqt, 4096, 1024, 1024, qub, qvb, u, v, nullptr);
    gemm_bf16<0><<<dim3(1024 / 128, 2048 / 128), 256, 0, stream>>>(
        Pemb, Wpt, 2048, 1024, 1024, pb, nullptr, nullptr, nullptr, nullptr);
    vtrans_kernel<<<dim3(J_ / 64, 1024 / 64, B_), 256, 0, stream>>>(kvb, vtg);

    flash_kernel<<<dim3(16, B_ * H_), 256, 0, stream>>>(qub, qvb, kvb, vtg, pb, awvb);

    gemm_bf16<2><<<dim3(1024 / 128, 4096 / 128), 256, 0, stream>>>(
        awvb, Wot, 4096, 1024, 1024, nullptr, nullptr, inputMHA, nullptr, opre);
    ln_kernel<<<S_ * B_, 256, 0, stream>>>(opre, gamma, beta, out);
}